// Round 3
// baseline (226.558 us; speedup 1.0000x reference)
//
#include <hip/hip_runtime.h>

#define NK 21      // classes
#define NC 256     // channels
#define NSRC 64    // source h/w
#define NOUT 256   // mask h/w
#define NB 8       // batch
#define EPS 1e-6f
#define KSPLIT 11  // classes per z-block (z=0: k 0..10, z=1: k 11..20)

// ---------------------------------------------------------------------------
// Main kernel. Grid (64, NB, 2): one block per (source row, image, k-half).
// Phase 1: bilinear-adjoint weight map W[<=11][64] in LDS from the mask.
// Phase 2: thread = channel; prefetch feats row (16x float4) and dot with W.
// Epilogue: per-strip partials psum[B][64][K][C], pcnt[B][64][K].
// ---------------------------------------------------------------------------
__global__ __launch_bounds__(256)
void proto_main(const float* __restrict__ feats,
                const int* __restrict__ masks,
                float* __restrict__ psum,
                float* __restrict__ pcnt) {
  __shared__ __align__(16) float Wl[KSPLIT * 64];
  __shared__ int hist[KSPLIT];

  const int tid = threadIdx.x;
  const int r0 = blockIdx.x;            // source row 0..63
  const int b = blockIdx.y;             // image
  const int klo = blockIdx.z * KSPLIT;  // 0 or 11
  const int kcnt = (klo + KSPLIT > NK) ? (NK - klo) : KSPLIT;  // 11 or 10

  for (int i = tid; i < KSPLIT * 64; i += 256) Wl[i] = 0.f;
  if (tid < KSPLIT) hist[tid] = 0;
  __syncthreads();

  // ---- Phase 1: output rows touching source row r0: y in [4r0-2, 4r0+5] ----
  int ylo = 4 * r0 - 2; if (ylo < 0) ylo = 0;
  int yhi = 4 * r0 + 5; if (yhi > NOUT - 1) yhi = NOUT - 1;
  const int npix = (yhi - ylo + 1) * NOUT;
  const int own_lo = 4 * r0, own_hi = 4 * r0 + 4;  // count-ownership rows

  for (int i = tid; i < npix; i += 256) {
    const int x = i & (NOUT - 1);
    const int y = ylo + (i >> 8);
    const int lbl = masks[((size_t)b * NOUT + y) * NOUT + x];
    const int lk = lbl - klo;
    if ((unsigned)lk < (unsigned)kcnt) {
      // y taps: src = 0.25*y - 0.375 (half-pixel, 4x up)
      const int ry = y >> 2, py = y & 3;
      const int j0y = (py < 2) ? ry - 1 : ry;
      const float fy = (py == 0) ? 0.625f : (py == 1) ? 0.875f
                     : (py == 2) ? 0.125f : 0.375f;
      const int rx = x >> 2, px = x & 3;
      const int j0x = (px < 2) ? rx - 1 : rx;
      const float fx = (px == 0) ? 0.625f : (px == 1) ? 0.875f
                     : (px == 2) ? 0.125f : 0.375f;

      const int cx0 = (j0x < 0) ? 0 : j0x;
      const int cx1 = (j0x + 1 > NSRC - 1) ? NSRC - 1 : j0x + 1;
      const float wx0 = 1.f - fx, wx1 = fx;
      const int ry0 = (j0y < 0) ? 0 : j0y;
      const int ry1 = (j0y + 1 > NSRC - 1) ? NSRC - 1 : j0y + 1;
      const float wy0 = 1.f - fy, wy1 = fy;

      float* Wk = &Wl[lk * 64];
      if (ry0 == r0) {
        atomicAdd(&Wk[cx0], wy0 * wx0);
        atomicAdd(&Wk[cx1], wy0 * wx1);
      }
      if (ry1 == r0) {
        atomicAdd(&Wk[cx0], wy1 * wx0);
        atomicAdd(&Wk[cx1], wy1 * wx1);
      }
      if (y >= own_lo && y < own_hi) atomicAdd(&hist[lk], 1);
    }
  }
  __syncthreads();

  // ---- Phase 2: per-channel dot with weight maps ----
  const int c = tid;
  const float4* fbase =
      (const float4*)(feats + ((size_t)(b * NC + c) << 12) + (size_t)r0 * 64);

  float4 f[16];
#pragma unroll
  for (int j = 0; j < 16; ++j) f[j] = fbase[j];  // 16 loads in flight

  float acc[KSPLIT];
#pragma unroll
  for (int kk = 0; kk < KSPLIT; ++kk) acc[kk] = 0.f;

#pragma unroll
  for (int kk = 0; kk < KSPLIT; ++kk) {
    const float4* w = (const float4*)&Wl[kk * 64];
    float a = 0.f;
#pragma unroll
    for (int j = 0; j < 16; ++j) {
      const float4 ww = w[j];  // broadcast ds_read_b128
      a = fmaf(f[j].x, ww.x, a);
      a = fmaf(f[j].y, ww.y, a);
      a = fmaf(f[j].z, ww.z, a);
      a = fmaf(f[j].w, ww.w, a);
    }
    acc[kk] = a;
  }

  float* dst = psum + ((size_t)(b * 64 + r0) * NK + klo) * NC + c;
#pragma unroll
  for (int kk = 0; kk < KSPLIT; ++kk)
    if (kk < kcnt) dst[kk * NC] = acc[kk];
  if (tid < kcnt)
    pcnt[(size_t)(b * 64 + r0) * NK + klo + tid] = (float)hist[tid];
}

// ---------------------------------------------------------------------------
// Finalize (fast path): grid (NK, NB); compile-time 64-strip unrolled loop.
// out[k][c] += sum_st psum / (sum_st cnt + eps) / 8   (atomic over b)
// ---------------------------------------------------------------------------
__global__ __launch_bounds__(256)
void proto_final64(const float* __restrict__ psum,
                   const float* __restrict__ pcnt,
                   float* __restrict__ out) {
  const int k = blockIdx.x;   // 0..20
  const int b = blockIdx.y;   // 0..7
  const int c = threadIdx.x;  // 0..255
  float s = 0.f, cnt = 0.f;
#pragma unroll
  for (int st = 0; st < 64; ++st) {
    s += psum[((size_t)(b * 64 + st) * NK + k) * NC + c];  // coalesced, in-flight
    cnt += pcnt[(size_t)(b * 64 + st) * NK + k];           // uniform/broadcast
  }
  atomicAdd(&out[k * NC + c], s / (cnt + EPS) * 0.125f);
}

// ---------------------------------------------------------------------------
// Fallback path (tiny ws): R=2 strips, global-atomic accumulation.
// ---------------------------------------------------------------------------
__global__ __launch_bounds__(256)
void proto_main_atomic(const float* __restrict__ feats,
                       const int* __restrict__ masks,
                       float* __restrict__ psum,   // [B][K][C]
                       float* __restrict__ pcnt) { // [B][K]
  constexpr int R = 2;
  __shared__ __align__(16) float Wl[NK * R * 64];
  __shared__ int hist[NK];
  const int tid = threadIdx.x;
  const int strip = blockIdx.x;
  const int b = blockIdx.y;
  const int r0 = strip * R;

  for (int i = tid; i < NK * R * 64; i += 256) Wl[i] = 0.f;
  if (tid < NK) hist[tid] = 0;
  __syncthreads();

  int ylo = 4 * r0 - 2; if (ylo < 0) ylo = 0;
  int yhi = 4 * (r0 + R - 1) + 5; if (yhi > NOUT - 1) yhi = NOUT - 1;
  const int npix = (yhi - ylo + 1) * NOUT;
  const int own_lo = 4 * r0, own_hi = 4 * r0 + 4 * R;

  for (int i = tid; i < npix; i += 256) {
    const int x = i & (NOUT - 1);
    const int y = ylo + (i >> 8);
    const int lbl = masks[((size_t)b * NOUT + y) * NOUT + x];
    if ((unsigned)lbl < NK) {
      const int ry = y >> 2, py = y & 3;
      const int j0y = (py < 2) ? ry - 1 : ry;
      const float fy = (py == 0) ? 0.625f : (py == 1) ? 0.875f
                     : (py == 2) ? 0.125f : 0.375f;
      const int rx = x >> 2, px = x & 3;
      const int j0x = (px < 2) ? rx - 1 : rx;
      const float fx = (px == 0) ? 0.625f : (px == 1) ? 0.875f
                     : (px == 2) ? 0.125f : 0.375f;
      const int cx0 = (j0x < 0) ? 0 : j0x;
      const int cx1 = (j0x + 1 > NSRC - 1) ? NSRC - 1 : j0x + 1;
      const float wx0 = 1.f - fx, wx1 = fx;
      const int ry0 = (j0y < 0) ? 0 : j0y;
      const int ry1 = (j0y + 1 > NSRC - 1) ? NSRC - 1 : j0y + 1;
      const float wy0 = 1.f - fy, wy1 = fy;
      float* Wk = &Wl[lbl * (R * 64)];
      const int sr0 = ry0 - r0, sr1 = ry1 - r0;
      if (sr0 >= 0 && sr0 < R) {
        atomicAdd(&Wk[sr0 * 64 + cx0], wy0 * wx0);
        atomicAdd(&Wk[sr0 * 64 + cx1], wy0 * wx1);
      }
      if (sr1 >= 0 && sr1 < R) {
        atomicAdd(&Wk[sr1 * 64 + cx0], wy1 * wx0);
        atomicAdd(&Wk[sr1 * 64 + cx1], wy1 * wx1);
      }
      if (y >= own_lo && y < own_hi) atomicAdd(&hist[lbl], 1);
    }
  }
  __syncthreads();

  const int c = tid;
  const float4* fbase =
      (const float4*)(feats + ((size_t)(b * NC + c) << 12) + (size_t)r0 * 64);
  float acc[NK];
#pragma unroll
  for (int k = 0; k < NK; ++k) acc[k] = 0.f;
  for (int rr = 0; rr < R; ++rr) {
    float4 f[16];
#pragma unroll
    for (int j = 0; j < 16; ++j) f[j] = fbase[rr * 16 + j];
#pragma unroll
    for (int k = 0; k < NK; ++k) {
      const float4* w = (const float4*)&Wl[(k * R + rr) * 64];
      float a = acc[k];
#pragma unroll
      for (int j = 0; j < 16; ++j) {
        const float4 ww = w[j];
        a = fmaf(f[j].x, ww.x, a);
        a = fmaf(f[j].y, ww.y, a);
        a = fmaf(f[j].z, ww.z, a);
        a = fmaf(f[j].w, ww.w, a);
      }
      acc[k] = a;
    }
  }
#pragma unroll
  for (int k = 0; k < NK; ++k)
    atomicAdd(&psum[((size_t)b * NK + k) * NC + c], acc[k]);
  if (tid < NK) atomicAdd(&pcnt[(size_t)b * NK + tid], (float)hist[tid]);
}

__global__ __launch_bounds__(256)
void proto_final1(const float* __restrict__ psum,
                  const float* __restrict__ pcnt,
                  float* __restrict__ out) {
  const int k = blockIdx.x;
  const int b = blockIdx.y;
  const int c = threadIdx.x;
  const float s = psum[((size_t)b * NK + k) * NC + c];
  const float cnt = pcnt[(size_t)b * NK + k];
  atomicAdd(&out[k * NC + c], s / (cnt + EPS) * 0.125f);
}

extern "C" void kernel_launch(void* const* d_in, const int* in_sizes, int n_in,
                              void* d_out, int out_size, void* d_ws, size_t ws_size,
                              hipStream_t stream) {
  const float* feats = (const float*)d_in[0];
  const int* masks = (const int*)d_in[1];
  float* out = (float*)d_out;

  const size_t need1 = (size_t)NB * 64 * NK * (NC + 1) * 4;  // ~11.05 MB

  hipMemsetAsync(d_out, 0, (size_t)out_size * 4, stream);

  float* psum = (float*)d_ws;
  if (ws_size >= need1) {
    float* pcnt = psum + (size_t)NB * 64 * NK * NC;
    proto_main<<<dim3(64, NB, 2), 256, 0, stream>>>(feats, masks, psum, pcnt);
    proto_final64<<<dim3(NK, NB), 256, 0, stream>>>(psum, pcnt, out);
  } else {
    float* pcnt = psum + (size_t)NB * NK * NC;
    hipMemsetAsync(d_ws, 0, ((size_t)NB * NK * NC + (size_t)NB * NK) * 4, stream);
    proto_main_atomic<<<dim3(32, NB), 256, 0, stream>>>(feats, masks, psum, pcnt);
    proto_final1<<<dim3(NK, NB), 256, 0, stream>>>(psum, pcnt, out);
  }
}

// Round 4
// 120.151 us; speedup vs baseline: 1.8856x; 1.8856x over previous
//
#include <hip/hip_runtime.h>

#define NK 21      // classes
#define NC 256     // channels
#define NSRC 64    // source h/w
#define NOUT 256   // mask h/w
#define NB 8       // batch
#define EPS 1e-6f

// ---------------------------------------------------------------------------
// Main kernel. Grid (64, NB): one block per (source row, image).
// Phase 1: bilinear-adjoint weight map W[21][64] in LDS from the mask rows
//          whose taps touch source row r0 (y in [4r0-2, 4r0+5], clamped).
// Phase 2: thread = channel; prefetch feats row (16x float4), dot with W
//          in 4-float4 chunks per class (bounded register pressure).
// Epilogue: per-row partials psum[B][64][K][C], pcnt[B][64][K]. No atomics.
// __launch_bounds__(256,4): cap 128 VGPR — R3's 256-VGPR spill (281 MB
// scratch writes) came from unbounded LDS-read hoisting.
// ---------------------------------------------------------------------------
__global__ __launch_bounds__(256, 4)
void proto_main(const float* __restrict__ feats,
                const int* __restrict__ masks,
                float* __restrict__ psum,
                float* __restrict__ pcnt) {
  __shared__ __align__(16) float Wl[NK * 64];
  __shared__ int hist[NK];

  const int tid = threadIdx.x;
  const int r0 = blockIdx.x;  // source row 0..63
  const int b = blockIdx.y;   // image

  for (int i = tid; i < NK * 64; i += 256) Wl[i] = 0.f;
  if (tid < NK) hist[tid] = 0;
  __syncthreads();

  // ---- Phase 1 ----
  int ylo = 4 * r0 - 2; if (ylo < 0) ylo = 0;
  int yhi = 4 * r0 + 5; if (yhi > NOUT - 1) yhi = NOUT - 1;
  const int npix = (yhi - ylo + 1) * NOUT;
  const int own_lo = 4 * r0, own_hi = 4 * r0 + 4;  // count-ownership rows

  for (int i = tid; i < npix; i += 256) {
    const int x = i & (NOUT - 1);
    const int y = ylo + (i >> 8);
    const int lbl = masks[((size_t)b * NOUT + y) * NOUT + x];
    if ((unsigned)lbl < NK) {
      // src = 0.25*y - 0.375 (half-pixel 4x); taps j0, j0+1, clamped
      const int ry = y >> 2, py = y & 3;
      const int j0y = (py < 2) ? ry - 1 : ry;
      const float fy = (py == 0) ? 0.625f : (py == 1) ? 0.875f
                     : (py == 2) ? 0.125f : 0.375f;
      const int rx = x >> 2, px = x & 3;
      const int j0x = (px < 2) ? rx - 1 : rx;
      const float fx = (px == 0) ? 0.625f : (px == 1) ? 0.875f
                     : (px == 2) ? 0.125f : 0.375f;

      const int cx0 = (j0x < 0) ? 0 : j0x;
      const int cx1 = (j0x + 1 > NSRC - 1) ? NSRC - 1 : j0x + 1;
      const float wx0 = 1.f - fx, wx1 = fx;
      const int ry0 = (j0y < 0) ? 0 : j0y;
      const int ry1 = (j0y + 1 > NSRC - 1) ? NSRC - 1 : j0y + 1;
      const float wy0 = 1.f - fy, wy1 = fy;

      float* Wk = &Wl[lbl * 64];
      if (ry0 == r0) {
        atomicAdd(&Wk[cx0], wy0 * wx0);
        atomicAdd(&Wk[cx1], wy0 * wx1);
      }
      if (ry1 == r0) {
        atomicAdd(&Wk[cx0], wy1 * wx0);
        atomicAdd(&Wk[cx1], wy1 * wx1);
      }
      if (y >= own_lo && y < own_hi) atomicAdd(&hist[lbl], 1);
    }
  }
  __syncthreads();

  // ---- Phase 2 ----
  const int c = tid;
  const float4* fbase =
      (const float4*)(feats + ((size_t)(b * NC + c) << 12) + (size_t)r0 * 64);

  float4 f[16];
#pragma unroll
  for (int j = 0; j < 16; ++j) f[j] = fbase[j];  // 16 loads, one vmcnt wait

  float acc[NK];
#pragma unroll
  for (int k = 0; k < NK; ++k) acc[k] = 0.f;

  const float4* wb = (const float4*)Wl;
#pragma clang loop unroll(disable)
  for (int ch = 0; ch < 4; ++ch) {  // 4 chunks of 4 float4 — bounds LDS live range
    const float4 f0 = f[ch * 4 + 0];
    const float4 f1 = f[ch * 4 + 1];
    const float4 f2 = f[ch * 4 + 2];
    const float4 f3 = f[ch * 4 + 3];
#pragma unroll
    for (int k = 0; k < NK; ++k) {
      const float4 w0 = wb[k * 16 + ch * 4 + 0];  // broadcast ds_read_b128
      const float4 w1 = wb[k * 16 + ch * 4 + 1];
      const float4 w2 = wb[k * 16 + ch * 4 + 2];
      const float4 w3 = wb[k * 16 + ch * 4 + 3];
      float a = acc[k];
      a = fmaf(f0.x, w0.x, a); a = fmaf(f0.y, w0.y, a);
      a = fmaf(f0.z, w0.z, a); a = fmaf(f0.w, w0.w, a);
      a = fmaf(f1.x, w1.x, a); a = fmaf(f1.y, w1.y, a);
      a = fmaf(f1.z, w1.z, a); a = fmaf(f1.w, w1.w, a);
      a = fmaf(f2.x, w2.x, a); a = fmaf(f2.y, w2.y, a);
      a = fmaf(f2.z, w2.z, a); a = fmaf(f2.w, w2.w, a);
      a = fmaf(f3.x, w3.x, a); a = fmaf(f3.y, w3.y, a);
      a = fmaf(f3.z, w3.z, a); a = fmaf(f3.w, w3.w, a);
      acc[k] = a;
    }
  }

  float* dst = psum + ((size_t)(b * 64 + r0) * NK) * NC + c;
#pragma unroll
  for (int k = 0; k < NK; ++k) dst[k * NC] = acc[k];  // coalesced per k
  if (tid < NK) pcnt[(size_t)(b * 64 + r0) * NK + tid] = (float)hist[tid];
}

// ---------------------------------------------------------------------------
// Finalize: grid (NK, NB); compile-time 64-row unrolled loop (loads batched
// in flight). out[k][c] += sum_r psum / (sum_r cnt + eps) / 8  (atomic over b)
// ---------------------------------------------------------------------------
__global__ __launch_bounds__(256)
void proto_final64(const float* __restrict__ psum,
                   const float* __restrict__ pcnt,
                   float* __restrict__ out) {
  const int k = blockIdx.x;   // 0..20
  const int b = blockIdx.y;   // 0..7
  const int c = threadIdx.x;  // 0..255
  float s = 0.f, cnt = 0.f;
#pragma unroll
  for (int st = 0; st < 64; ++st) {
    s += psum[((size_t)(b * 64 + st) * NK + k) * NC + c];  // coalesced
    cnt += pcnt[(size_t)(b * 64 + st) * NK + k];           // uniform -> s_load
  }
  atomicAdd(&out[k * NC + c], s / (cnt + EPS) * 0.125f);
}

// ---------------------------------------------------------------------------
// Fallback (tiny ws): global-atomic accumulation into psum[B][K][C].
// ---------------------------------------------------------------------------
__global__ __launch_bounds__(256, 4)
void proto_main_atomic(const float* __restrict__ feats,
                       const int* __restrict__ masks,
                       float* __restrict__ psum,   // [B][K][C]
                       float* __restrict__ pcnt) { // [B][K]
  __shared__ __align__(16) float Wl[NK * 64];
  __shared__ int hist[NK];
  const int tid = threadIdx.x;
  const int r0 = blockIdx.x;
  const int b = blockIdx.y;

  for (int i = tid; i < NK * 64; i += 256) Wl[i] = 0.f;
  if (tid < NK) hist[tid] = 0;
  __syncthreads();

  int ylo = 4 * r0 - 2; if (ylo < 0) ylo = 0;
  int yhi = 4 * r0 + 5; if (yhi > NOUT - 1) yhi = NOUT - 1;
  const int npix = (yhi - ylo + 1) * NOUT;
  const int own_lo = 4 * r0, own_hi = 4 * r0 + 4;

  for (int i = tid; i < npix; i += 256) {
    const int x = i & (NOUT - 1);
    const int y = ylo + (i >> 8);
    const int lbl = masks[((size_t)b * NOUT + y) * NOUT + x];
    if ((unsigned)lbl < NK) {
      const int ry = y >> 2, py = y & 3;
      const int j0y = (py < 2) ? ry - 1 : ry;
      const float fy = (py == 0) ? 0.625f : (py == 1) ? 0.875f
                     : (py == 2) ? 0.125f : 0.375f;
      const int rx = x >> 2, px = x & 3;
      const int j0x = (px < 2) ? rx - 1 : rx;
      const float fx = (px == 0) ? 0.625f : (px == 1) ? 0.875f
                     : (px == 2) ? 0.125f : 0.375f;
      const int cx0 = (j0x < 0) ? 0 : j0x;
      const int cx1 = (j0x + 1 > NSRC - 1) ? NSRC - 1 : j0x + 1;
      const float wx0 = 1.f - fx, wx1 = fx;
      const int ry0 = (j0y < 0) ? 0 : j0y;
      const int ry1 = (j0y + 1 > NSRC - 1) ? NSRC - 1 : j0y + 1;
      const float wy0 = 1.f - fy, wy1 = fy;
      float* Wk = &Wl[lbl * 64];
      if (ry0 == r0) {
        atomicAdd(&Wk[cx0], wy0 * wx0);
        atomicAdd(&Wk[cx1], wy0 * wx1);
      }
      if (ry1 == r0) {
        atomicAdd(&Wk[cx0], wy1 * wx0);
        atomicAdd(&Wk[cx1], wy1 * wx1);
      }
      if (y >= own_lo && y < own_hi) atomicAdd(&hist[lbl], 1);
    }
  }
  __syncthreads();

  const int c = tid;
  const float4* fbase =
      (const float4*)(feats + ((size_t)(b * NC + c) << 12) + (size_t)r0 * 64);
  float4 f[16];
#pragma unroll
  for (int j = 0; j < 16; ++j) f[j] = fbase[j];
  float acc[NK];
#pragma unroll
  for (int k = 0; k < NK; ++k) acc[k] = 0.f;
  const float4* wb = (const float4*)Wl;
#pragma clang loop unroll(disable)
  for (int ch = 0; ch < 4; ++ch) {
    const float4 f0 = f[ch * 4 + 0];
    const float4 f1 = f[ch * 4 + 1];
    const float4 f2 = f[ch * 4 + 2];
    const float4 f3 = f[ch * 4 + 3];
#pragma unroll
    for (int k = 0; k < NK; ++k) {
      const float4 w0 = wb[k * 16 + ch * 4 + 0];
      const float4 w1 = wb[k * 16 + ch * 4 + 1];
      const float4 w2 = wb[k * 16 + ch * 4 + 2];
      const float4 w3 = wb[k * 16 + ch * 4 + 3];
      float a = acc[k];
      a = fmaf(f0.x, w0.x, a); a = fmaf(f0.y, w0.y, a);
      a = fmaf(f0.z, w0.z, a); a = fmaf(f0.w, w0.w, a);
      a = fmaf(f1.x, w1.x, a); a = fmaf(f1.y, w1.y, a);
      a = fmaf(f1.z, w1.z, a); a = fmaf(f1.w, w1.w, a);
      a = fmaf(f2.x, w2.x, a); a = fmaf(f2.y, w2.y, a);
      a = fmaf(f2.z, w2.z, a); a = fmaf(f2.w, w2.w, a);
      a = fmaf(f3.x, w3.x, a); a = fmaf(f3.y, w3.y, a);
      a = fmaf(f3.z, w3.z, a); a = fmaf(f3.w, w3.w, a);
      acc[k] = a;
    }
  }
#pragma unroll
  for (int k = 0; k < NK; ++k)
    atomicAdd(&psum[((size_t)b * NK + k) * NC + c], acc[k]);
  if (tid < NK) atomicAdd(&pcnt[(size_t)b * NK + tid], (float)hist[tid]);
}

__global__ __launch_bounds__(256)
void proto_final1(const float* __restrict__ psum,
                  const float* __restrict__ pcnt,
                  float* __restrict__ out) {
  const int k = blockIdx.x;
  const int b = blockIdx.y;
  const int c = threadIdx.x;
  const float s = psum[((size_t)b * NK + k) * NC + c];
  const float cnt = pcnt[(size_t)b * NK + k];
  atomicAdd(&out[k * NC + c], s / (cnt + EPS) * 0.125f);
}

extern "C" void kernel_launch(void* const* d_in, const int* in_sizes, int n_in,
                              void* d_out, int out_size, void* d_ws, size_t ws_size,
                              hipStream_t stream) {
  const float* feats = (const float*)d_in[0];
  const int* masks = (const int*)d_in[1];
  float* out = (float*)d_out;

  const size_t need1 = (size_t)NB * 64 * NK * (NC + 1) * 4;  // ~11.05 MB

  hipMemsetAsync(d_out, 0, (size_t)out_size * 4, stream);

  float* psum = (float*)d_ws;
  if (ws_size >= need1) {
    float* pcnt = psum + (size_t)NB * 64 * NK * NC;
    proto_main<<<dim3(64, NB), 256, 0, stream>>>(feats, masks, psum, pcnt);
    proto_final64<<<dim3(NK, NB), 256, 0, stream>>>(psum, pcnt, out);
  } else {
    float* pcnt = psum + (size_t)NB * NK * NC;
    hipMemsetAsync(d_ws, 0, ((size_t)NB * NK * NC + (size_t)NB * NK) * 4, stream);
    proto_main_atomic<<<dim3(64, NB), 256, 0, stream>>>(feats, masks, psum, pcnt);
    proto_final1<<<dim3(NK, NB), 256, 0, stream>>>(psum, pcnt, out);
  }
}

// Round 5
// 110.603 us; speedup vs baseline: 2.0484x; 1.0863x over previous
//
#include <hip/hip_runtime.h>

#define NK 21      // classes
#define NC 256     // channels
#define NSRC 64    // source h/w
#define NOUT 256   // mask h/w
#define NB 8       // batch
#define EPS 1e-6f

// ---------------------------------------------------------------------------
// Main kernel. Grid (64, NB, 2): one block per (source row r0, image b,
// column-half z). Columns [32z, 32z+32) of source row r0.
//
// Phase 0: prefetch this thread's 32 feats floats (8x float4, named regs)
//          BEFORE phase 1 — HBM latency hides under the mask scatter.
// Phase 1: bilinear-adjoint weights W[21][32] in LDS from mask pixels
//          y in [4r0-2, 4r0+5], x in a constant 130-wide window (the only
//          x whose taps can land in this column-half).
// Phase 2: thread = channel; acc[21] via LDS-broadcast float4 reads.
// Epilogue: global atomicAdd into L2-resident psum[B][K][C] (172 KB).
// __launch_bounds__(256,4): cap 128 VGPR (R3's spill lesson).
// ---------------------------------------------------------------------------
__global__ __launch_bounds__(256, 4)
void proto_main(const float* __restrict__ feats,
                const int* __restrict__ masks,
                float* __restrict__ psum,   // [B][K][C] atomic
                float* __restrict__ pcnt) { // [B][K]    atomic
  __shared__ __align__(16) float Wl[NK * 32];
  __shared__ int hist[NK];

  const int tid = threadIdx.x;
  const int r0 = blockIdx.x;  // source row 0..63
  const int b = blockIdx.y;   // image
  const int z = blockIdx.z;   // column half 0/1

  // ---- Phase 0: early feats prefetch (named regs -> stays in VGPRs) ----
  const float4* fbase = (const float4*)(
      feats + ((size_t)(b * NC + tid) << 12) + (size_t)r0 * 64 + 32 * z);
  const float4 f0 = fbase[0], f1 = fbase[1], f2 = fbase[2], f3 = fbase[3];
  const float4 f4 = fbase[4], f5 = fbase[5], f6 = fbase[6], f7 = fbase[7];

  for (int i = tid; i < NK * 32; i += 256) Wl[i] = 0.f;
  if (tid < NK) hist[tid] = 0;
  __syncthreads();

  // ---- Phase 1 ----
  int ylo = 4 * r0 - 2; if (ylo < 0) ylo = 0;
  int yhi = 4 * r0 + 5; if (yhi > NOUT - 1) yhi = NOUT - 1;
  const int xlo = z ? 126 : 0;  // constant 130-wide window per half
  const int npix = (yhi - ylo + 1) * 130;
  const int own_lo = 4 * r0;    // count ownership: y in [4r0,4r0+4), x-half z

  for (int i = tid; i < npix; i += 256) {
    const int x = xlo + i % 130;
    const int y = ylo + i / 130;
    const int lbl = masks[((size_t)b * NOUT + y) * NOUT + x];
    if ((unsigned)lbl < NK) {
      // src = 0.25*t - 0.375 (half-pixel 4x); taps j0, j0+1, clamped
      const int ry = y >> 2, py = y & 3;
      const int j0y = (py < 2) ? ry - 1 : ry;
      const float fy = (py == 0) ? 0.625f : (py == 1) ? 0.875f
                     : (py == 2) ? 0.125f : 0.375f;
      const int rx = x >> 2, px = x & 3;
      const int j0x = (px < 2) ? rx - 1 : rx;
      const float fx = (px == 0) ? 0.625f : (px == 1) ? 0.875f
                     : (px == 2) ? 0.125f : 0.375f;

      const int cx0 = (j0x < 0) ? 0 : j0x;
      const int cx1 = (j0x + 1 > NSRC - 1) ? NSRC - 1 : j0x + 1;
      const float wx0 = 1.f - fx, wx1 = fx;
      const int ry0 = (j0y < 0) ? 0 : j0y;
      const int ry1 = (j0y + 1 > NSRC - 1) ? NSRC - 1 : j0y + 1;
      const float wy0 = 1.f - fy, wy1 = fy;

      float* Wk = &Wl[lbl * 32];
      if (ry0 == r0) {
        if ((cx0 >> 5) == z) atomicAdd(&Wk[cx0 & 31], wy0 * wx0);
        if ((cx1 >> 5) == z) atomicAdd(&Wk[cx1 & 31], wy0 * wx1);
      }
      if (ry1 == r0) {
        if ((cx0 >> 5) == z) atomicAdd(&Wk[cx0 & 31], wy1 * wx0);
        if ((cx1 >> 5) == z) atomicAdd(&Wk[cx1 & 31], wy1 * wx1);
      }
      if (y >= own_lo && y < own_lo + 4 && (x >> 7) == z)
        atomicAdd(&hist[lbl], 1);
    }
  }
  __syncthreads();

  // ---- Phase 2: acc[k] = sum_s W[k][s] * F[s] ----
  float acc[NK];
#pragma unroll
  for (int k = 0; k < NK; ++k) acc[k] = 0.f;

  const float4* wb = (const float4*)Wl;
#pragma unroll
  for (int k = 0; k < NK; ++k) {  // chunk 0: s 0..15
    const float4 w0 = wb[k * 8 + 0], w1 = wb[k * 8 + 1];
    const float4 w2 = wb[k * 8 + 2], w3 = wb[k * 8 + 3];
    float a = acc[k];
    a = fmaf(f0.x, w0.x, a); a = fmaf(f0.y, w0.y, a);
    a = fmaf(f0.z, w0.z, a); a = fmaf(f0.w, w0.w, a);
    a = fmaf(f1.x, w1.x, a); a = fmaf(f1.y, w1.y, a);
    a = fmaf(f1.z, w1.z, a); a = fmaf(f1.w, w1.w, a);
    a = fmaf(f2.x, w2.x, a); a = fmaf(f2.y, w2.y, a);
    a = fmaf(f2.z, w2.z, a); a = fmaf(f2.w, w2.w, a);
    a = fmaf(f3.x, w3.x, a); a = fmaf(f3.y, w3.y, a);
    a = fmaf(f3.z, w3.z, a); a = fmaf(f3.w, w3.w, a);
    acc[k] = a;
  }
#pragma unroll
  for (int k = 0; k < NK; ++k) {  // chunk 1: s 16..31
    const float4 w4 = wb[k * 8 + 4], w5 = wb[k * 8 + 5];
    const float4 w6 = wb[k * 8 + 6], w7 = wb[k * 8 + 7];
    float a = acc[k];
    a = fmaf(f4.x, w4.x, a); a = fmaf(f4.y, w4.y, a);
    a = fmaf(f4.z, w4.z, a); a = fmaf(f4.w, w4.w, a);
    a = fmaf(f5.x, w5.x, a); a = fmaf(f5.y, w5.y, a);
    a = fmaf(f5.z, w5.z, a); a = fmaf(f5.w, w5.w, a);
    a = fmaf(f6.x, w6.x, a); a = fmaf(f6.y, w6.y, a);
    a = fmaf(f6.z, w6.z, a); a = fmaf(f6.w, w6.w, a);
    a = fmaf(f7.x, w7.x, a); a = fmaf(f7.y, w7.y, a);
    a = fmaf(f7.z, w7.z, a); a = fmaf(f7.w, w7.w, a);
    acc[k] = a;
  }

  // ---- Epilogue: fire-and-forget atomics into L2-resident psum ----
#pragma unroll
  for (int k = 0; k < NK; ++k)
    atomicAdd(&psum[((size_t)b * NK + k) * NC + tid], acc[k]);
  if (tid < NK) atomicAdd(&pcnt[(size_t)b * NK + tid], (float)hist[tid]);
}

// ---------------------------------------------------------------------------
// Finalize: grid (NK); out[k][c] = (1/8) sum_b psum[b][k][c]/(pcnt[b][k]+eps)
// 172 KB, L2-hot, 8 unrolled loads per thread. Writes out directly.
// ---------------------------------------------------------------------------
__global__ __launch_bounds__(256)
void proto_final(const float* __restrict__ psum,
                 const float* __restrict__ pcnt,
                 float* __restrict__ out) {
  const int k = blockIdx.x;   // 0..20
  const int c = threadIdx.x;  // 0..255
  float a = 0.f;
#pragma unroll
  for (int b = 0; b < NB; ++b)
    a += psum[((size_t)b * NK + k) * NC + c] / (pcnt[(size_t)b * NK + k] + EPS);
  out[(size_t)k * NC + c] = a * 0.125f;
}

extern "C" void kernel_launch(void* const* d_in, const int* in_sizes, int n_in,
                              void* d_out, int out_size, void* d_ws, size_t ws_size,
                              hipStream_t stream) {
  const float* feats = (const float*)d_in[0];
  const int* masks = (const int*)d_in[1];
  float* out = (float*)d_out;

  float* psum = (float*)d_ws;                      // [B][K][C]
  float* pcnt = psum + (size_t)NB * NK * NC;       // [B][K]
  const size_t zbytes = ((size_t)NB * NK * NC + (size_t)NB * NK) * 4;  // ~173 KB

  hipMemsetAsync(d_ws, 0, zbytes, stream);
  proto_main<<<dim3(64, NB, 2), 256, 0, stream>>>(feats, masks, psum, pcnt);
  proto_final<<<dim3(NK), 256, 0, stream>>>(psum, pcnt, out);
}

// Round 6
// 101.355 us; speedup vs baseline: 2.2353x; 1.0912x over previous
//
#include <hip/hip_runtime.h>

#define NK 21      // classes
#define NC 256     // channels
#define NSRC 64    // source h/w
#define NOUT 256   // mask h/w
#define NB 8       // batch
#define NSL 128    // producer slices per image: 64 rows x 2 column-halves
#define EPS 1e-6f

// Native LDS fp32 atomic add (ds_add_f32) — avoids the CAS-loop lowering of
// plain atomicAdd(float*), which was R5's hypothesized 45us serialization.
__device__ __forceinline__ void lds_fadd(float* p, float v) {
  __hip_atomic_fetch_add(p, v, __ATOMIC_RELAXED, __HIP_MEMORY_SCOPE_WORKGROUP);
}

// ---------------------------------------------------------------------------
// Main kernel. Grid (64, NB, 2): (source row r0, image b, column-half z).
// Phase 0: prefetch this thread's 32 feats floats (8 named float4).
// Phase 1: bilinear-adjoint weights W[21][32] in LDS (native ds_add_f32).
// Phase 2: thread = channel; acc[21] via LDS-broadcast float4 reads.
// Epilogue: PLAIN coalesced stores to psum[B][NSL][K][C] — no atomics.
// ---------------------------------------------------------------------------
__global__ __launch_bounds__(256, 4)
void proto_main(const float* __restrict__ feats,
                const int* __restrict__ masks,
                float* __restrict__ psum,   // [B][NSL][K][C]
                float* __restrict__ pcnt) { // [B][NSL][K]
  __shared__ __align__(16) float Wl[NK * 32];
  __shared__ int hist[NK];

  const int tid = threadIdx.x;
  const int r0 = blockIdx.x;  // source row 0..63
  const int b = blockIdx.y;   // image
  const int z = blockIdx.z;   // column half 0/1

  // ---- Phase 0: early feats prefetch (named regs) ----
  const float4* fbase = (const float4*)(
      feats + ((size_t)(b * NC + tid) << 12) + (size_t)r0 * 64 + 32 * z);
  const float4 f0 = fbase[0], f1 = fbase[1], f2 = fbase[2], f3 = fbase[3];
  const float4 f4 = fbase[4], f5 = fbase[5], f6 = fbase[6], f7 = fbase[7];

  for (int i = tid; i < NK * 32; i += 256) Wl[i] = 0.f;
  if (tid < NK) hist[tid] = 0;
  __syncthreads();

  // ---- Phase 1 ----
  int ylo = 4 * r0 - 2; if (ylo < 0) ylo = 0;
  int yhi = 4 * r0 + 5; if (yhi > NOUT - 1) yhi = NOUT - 1;
  const int xlo = z ? 126 : 0;  // 130-wide window covers all taps of this half
  const int npix = (yhi - ylo + 1) * 130;
  const int own_lo = 4 * r0;    // count ownership: y in [4r0,4r0+4), x-half z

  for (int i = tid; i < npix; i += 256) {
    const int x = xlo + i % 130;
    const int y = ylo + i / 130;
    const int lbl = masks[((size_t)b * NOUT + y) * NOUT + x];
    if ((unsigned)lbl < NK) {
      // src = 0.25*t - 0.375 (half-pixel 4x); taps j0, j0+1, clamped
      const int ry = y >> 2, py = y & 3;
      const int j0y = (py < 2) ? ry - 1 : ry;
      const float fy = (py == 0) ? 0.625f : (py == 1) ? 0.875f
                     : (py == 2) ? 0.125f : 0.375f;
      const int rx = x >> 2, px = x & 3;
      const int j0x = (px < 2) ? rx - 1 : rx;
      const float fx = (px == 0) ? 0.625f : (px == 1) ? 0.875f
                     : (px == 2) ? 0.125f : 0.375f;

      const int cx0 = (j0x < 0) ? 0 : j0x;
      const int cx1 = (j0x + 1 > NSRC - 1) ? NSRC - 1 : j0x + 1;
      const float wx0 = 1.f - fx, wx1 = fx;
      const int ry0 = (j0y < 0) ? 0 : j0y;
      const int ry1 = (j0y + 1 > NSRC - 1) ? NSRC - 1 : j0y + 1;
      const float wy0 = 1.f - fy, wy1 = fy;

      float* Wk = &Wl[lbl * 32];
      if (ry0 == r0) {
        if ((cx0 >> 5) == z) lds_fadd(&Wk[cx0 & 31], wy0 * wx0);
        if ((cx1 >> 5) == z) lds_fadd(&Wk[cx1 & 31], wy0 * wx1);
      }
      if (ry1 == r0) {
        if ((cx0 >> 5) == z) lds_fadd(&Wk[cx0 & 31], wy1 * wx0);
        if ((cx1 >> 5) == z) lds_fadd(&Wk[cx1 & 31], wy1 * wx1);
      }
      if (y >= own_lo && y < own_lo + 4 && (x >> 7) == z)
        atomicAdd(&hist[lbl], 1);  // int: native ds_add
    }
  }
  __syncthreads();

  // ---- Phase 2: acc[k] = sum_s W[k][s] * F[s] ----
  float acc[NK];
#pragma unroll
  for (int k = 0; k < NK; ++k) acc[k] = 0.f;

  const float4* wb = (const float4*)Wl;
#pragma unroll
  for (int k = 0; k < NK; ++k) {  // s 0..15
    const float4 w0 = wb[k * 8 + 0], w1 = wb[k * 8 + 1];
    const float4 w2 = wb[k * 8 + 2], w3 = wb[k * 8 + 3];
    float a = acc[k];
    a = fmaf(f0.x, w0.x, a); a = fmaf(f0.y, w0.y, a);
    a = fmaf(f0.z, w0.z, a); a = fmaf(f0.w, w0.w, a);
    a = fmaf(f1.x, w1.x, a); a = fmaf(f1.y, w1.y, a);
    a = fmaf(f1.z, w1.z, a); a = fmaf(f1.w, w1.w, a);
    a = fmaf(f2.x, w2.x, a); a = fmaf(f2.y, w2.y, a);
    a = fmaf(f2.z, w2.z, a); a = fmaf(f2.w, w2.w, a);
    a = fmaf(f3.x, w3.x, a); a = fmaf(f3.y, w3.y, a);
    a = fmaf(f3.z, w3.z, a); a = fmaf(f3.w, w3.w, a);
    acc[k] = a;
  }
#pragma unroll
  for (int k = 0; k < NK; ++k) {  // s 16..31
    const float4 w4 = wb[k * 8 + 4], w5 = wb[k * 8 + 5];
    const float4 w6 = wb[k * 8 + 6], w7 = wb[k * 8 + 7];
    float a = acc[k];
    a = fmaf(f4.x, w4.x, a); a = fmaf(f4.y, w4.y, a);
    a = fmaf(f4.z, w4.z, a); a = fmaf(f4.w, w4.w, a);
    a = fmaf(f5.x, w5.x, a); a = fmaf(f5.y, w5.y, a);
    a = fmaf(f5.z, w5.z, a); a = fmaf(f5.w, w5.w, a);
    a = fmaf(f6.x, w6.x, a); a = fmaf(f6.y, w6.y, a);
    a = fmaf(f6.z, w6.z, a); a = fmaf(f6.w, w6.w, a);
    a = fmaf(f7.x, w7.x, a); a = fmaf(f7.y, w7.y, a);
    a = fmaf(f7.z, w7.z, a); a = fmaf(f7.w, w7.w, a);
    acc[k] = a;
  }

  // ---- Epilogue: plain coalesced stores, no atomics ----
  const int sl = r0 * 2 + z;
  float* dst = psum + ((size_t)(b * NSL + sl) * NK) * NC + tid;
#pragma unroll
  for (int k = 0; k < NK; ++k) dst[k * NC] = acc[k];
  if (tid < NK) pcnt[(size_t)(b * NSL + sl) * NK + tid] = (float)hist[tid];
}

// ---------------------------------------------------------------------------
// Finalize A: grid (NK, NB); reduce 128 slices (unrolled, loads in flight).
// tmp[b][k][c] = (sum_sl psum) / (sum_sl cnt + eps) * 0.125
// ---------------------------------------------------------------------------
__global__ __launch_bounds__(256)
void proto_finalA(const float* __restrict__ psum,
                  const float* __restrict__ pcnt,
                  float* __restrict__ tmp) {
  const int k = blockIdx.x;   // 0..20
  const int b = blockIdx.y;   // 0..7
  const int c = threadIdx.x;  // 0..255
  float s = 0.f, cnt = 0.f;
#pragma unroll
  for (int sl = 0; sl < NSL; ++sl) {
    s += psum[((size_t)(b * NSL + sl) * NK + k) * NC + c];  // coalesced
    cnt += pcnt[(size_t)(b * NSL + sl) * NK + k];           // uniform
  }
  tmp[((size_t)b * NK + k) * NC + c] = s / (cnt + EPS) * 0.125f;
}

// ---------------------------------------------------------------------------
// Finalize B: grid (NK); out[k][c] = sum_b tmp[b][k][c]  (L2-hot 172 KB)
// ---------------------------------------------------------------------------
__global__ __launch_bounds__(256)
void proto_finalB(const float* __restrict__ tmp,
                  float* __restrict__ out) {
  const int k = blockIdx.x;
  const int c = threadIdx.x;
  float a = 0.f;
#pragma unroll
  for (int b = 0; b < NB; ++b)
    a += tmp[((size_t)b * NK + k) * NC + c];
  out[(size_t)k * NC + c] = a;
}

extern "C" void kernel_launch(void* const* d_in, const int* in_sizes, int n_in,
                              void* d_out, int out_size, void* d_ws, size_t ws_size,
                              hipStream_t stream) {
  const float* feats = (const float*)d_in[0];
  const int* masks = (const int*)d_in[1];
  float* out = (float*)d_out;

  // ws layout: psum [B][NSL][K][C] (22.0 MB) | pcnt [B][NSL][K] (86 KB)
  //            | tmp [B][K][C] (172 KB).  ws is 256 MiB (poison fill showed
  //            268 MB) — fits with huge margin. All regions fully
  //            overwritten before read; no memset needed.
  float* psum = (float*)d_ws;
  float* pcnt = psum + (size_t)NB * NSL * NK * NC;
  float* tmp = pcnt + (size_t)NB * NSL * NK;

  proto_main<<<dim3(64, NB, 2), 256, 0, stream>>>(feats, masks, psum, pcnt);
  proto_finalA<<<dim3(NK, NB), 256, 0, stream>>>(psum, pcnt, tmp);
  proto_finalB<<<dim3(NK), 256, 0, stream>>>(tmp, out);
}

// Round 7
// 99.703 us; speedup vs baseline: 2.2723x; 1.0166x over previous
//
#include <hip/hip_runtime.h>

#define NK 21      // classes
#define NC 256     // channels
#define NSRC 64    // source h/w
#define NOUT 256   // mask h/w
#define NB 8       // batch
#define NSL 128    // producer slices per image: 64 rows x 2 column-halves
#define NG 8       // finalA slice-groups (NSL/16 per group)
#define EPS 1e-6f

// Native LDS fp32 atomic add (ds_add_f32). Plain atomicAdd(float*) lowers to
// a CAS loop — that was the invariant ~44us in R4/R5.
__device__ __forceinline__ void lds_fadd(float* p, float v) {
  __hip_atomic_fetch_add(p, v, __ATOMIC_RELAXED, __HIP_MEMORY_SCOPE_WORKGROUP);
}

// ---------------------------------------------------------------------------
// Main kernel. Grid (64, NB, 2): (source row r0, image b, column-half z).
// Phase 0: prefetch this thread's 32 feats floats (8 named float4).
// Phase 1: bilinear-adjoint weights W[21][32] in LDS (native ds_add_f32).
// Phase 2: thread = channel; acc[21] via LDS-broadcast float4 reads.
// Epilogue: plain coalesced stores to psum[B][NSL][K][C] — no atomics.
// ---------------------------------------------------------------------------
__global__ __launch_bounds__(256, 4)
void proto_main(const float* __restrict__ feats,
                const int* __restrict__ masks,
                float* __restrict__ psum,   // [B][NSL][K][C]
                float* __restrict__ pcnt) { // [B][NSL][K]
  __shared__ __align__(16) float Wl[NK * 32];
  __shared__ int hist[NK];

  const int tid = threadIdx.x;
  const int r0 = blockIdx.x;  // source row 0..63
  const int b = blockIdx.y;   // image
  const int z = blockIdx.z;   // column half 0/1

  // ---- Phase 0: early feats prefetch ----
  const float4* fbase = (const float4*)(
      feats + ((size_t)(b * NC + tid) << 12) + (size_t)r0 * 64 + 32 * z);
  const float4 f0 = fbase[0], f1 = fbase[1], f2 = fbase[2], f3 = fbase[3];
  const float4 f4 = fbase[4], f5 = fbase[5], f6 = fbase[6], f7 = fbase[7];

  for (int i = tid; i < NK * 32; i += 256) Wl[i] = 0.f;
  if (tid < NK) hist[tid] = 0;
  __syncthreads();

  // ---- Phase 1 ----
  int ylo = 4 * r0 - 2; if (ylo < 0) ylo = 0;
  int yhi = 4 * r0 + 5; if (yhi > NOUT - 1) yhi = NOUT - 1;
  const int xlo = z ? 126 : 0;  // 130-wide window covers all taps of this half
  const int npix = (yhi - ylo + 1) * 130;
  const int own_lo = 4 * r0;    // count ownership: y in [4r0,4r0+4), x-half z

  for (int i = tid; i < npix; i += 256) {
    const int x = xlo + i % 130;
    const int y = ylo + i / 130;
    const int lbl = masks[((size_t)b * NOUT + y) * NOUT + x];
    if ((unsigned)lbl < NK) {
      // src = 0.25*t - 0.375 (half-pixel 4x); taps j0, j0+1, clamped
      const int ry = y >> 2, py = y & 3;
      const int j0y = (py < 2) ? ry - 1 : ry;
      const float fy = (py == 0) ? 0.625f : (py == 1) ? 0.875f
                     : (py == 2) ? 0.125f : 0.375f;
      const int rx = x >> 2, px = x & 3;
      const int j0x = (px < 2) ? rx - 1 : rx;
      const float fx = (px == 0) ? 0.625f : (px == 1) ? 0.875f
                     : (px == 2) ? 0.125f : 0.375f;

      const int cx0 = (j0x < 0) ? 0 : j0x;
      const int cx1 = (j0x + 1 > NSRC - 1) ? NSRC - 1 : j0x + 1;
      const float wx0 = 1.f - fx, wx1 = fx;
      const int ry0 = (j0y < 0) ? 0 : j0y;
      const int ry1 = (j0y + 1 > NSRC - 1) ? NSRC - 1 : j0y + 1;
      const float wy0 = 1.f - fy, wy1 = fy;

      float* Wk = &Wl[lbl * 32];
      if (ry0 == r0) {
        if ((cx0 >> 5) == z) lds_fadd(&Wk[cx0 & 31], wy0 * wx0);
        if ((cx1 >> 5) == z) lds_fadd(&Wk[cx1 & 31], wy0 * wx1);
      }
      if (ry1 == r0) {
        if ((cx0 >> 5) == z) lds_fadd(&Wk[cx0 & 31], wy1 * wx0);
        if ((cx1 >> 5) == z) lds_fadd(&Wk[cx1 & 31], wy1 * wx1);
      }
      if (y >= own_lo && y < own_lo + 4 && (x >> 7) == z)
        atomicAdd(&hist[lbl], 1);  // int: native ds_add
    }
  }
  __syncthreads();

  // ---- Phase 2: acc[k] = sum_s W[k][s] * F[s] ----
  float acc[NK];
#pragma unroll
  for (int k = 0; k < NK; ++k) acc[k] = 0.f;

  const float4* wb = (const float4*)Wl;
#pragma unroll
  for (int k = 0; k < NK; ++k) {  // s 0..15
    const float4 w0 = wb[k * 8 + 0], w1 = wb[k * 8 + 1];
    const float4 w2 = wb[k * 8 + 2], w3 = wb[k * 8 + 3];
    float a = acc[k];
    a = fmaf(f0.x, w0.x, a); a = fmaf(f0.y, w0.y, a);
    a = fmaf(f0.z, w0.z, a); a = fmaf(f0.w, w0.w, a);
    a = fmaf(f1.x, w1.x, a); a = fmaf(f1.y, w1.y, a);
    a = fmaf(f1.z, w1.z, a); a = fmaf(f1.w, w1.w, a);
    a = fmaf(f2.x, w2.x, a); a = fmaf(f2.y, w2.y, a);
    a = fmaf(f2.z, w2.z, a); a = fmaf(f2.w, w2.w, a);
    a = fmaf(f3.x, w3.x, a); a = fmaf(f3.y, w3.y, a);
    a = fmaf(f3.z, w3.z, a); a = fmaf(f3.w, w3.w, a);
    acc[k] = a;
  }
#pragma unroll
  for (int k = 0; k < NK; ++k) {  // s 16..31
    const float4 w4 = wb[k * 8 + 4], w5 = wb[k * 8 + 5];
    const float4 w6 = wb[k * 8 + 6], w7 = wb[k * 8 + 7];
    float a = acc[k];
    a = fmaf(f4.x, w4.x, a); a = fmaf(f4.y, w4.y, a);
    a = fmaf(f4.z, w4.z, a); a = fmaf(f4.w, w4.w, a);
    a = fmaf(f5.x, w5.x, a); a = fmaf(f5.y, w5.y, a);
    a = fmaf(f5.z, w5.z, a); a = fmaf(f5.w, w5.w, a);
    a = fmaf(f6.x, w6.x, a); a = fmaf(f6.y, w6.y, a);
    a = fmaf(f6.z, w6.z, a); a = fmaf(f6.w, w6.w, a);
    a = fmaf(f7.x, w7.x, a); a = fmaf(f7.y, w7.y, a);
    a = fmaf(f7.z, w7.z, a); a = fmaf(f7.w, w7.w, a);
    acc[k] = a;
  }

  // ---- Epilogue: plain coalesced stores ----
  const int sl = r0 * 2 + z;
  float* dst = psum + ((size_t)(b * NSL + sl) * NK) * NC + tid;
#pragma unroll
  for (int k = 0; k < NK; ++k) dst[k * NC] = acc[k];
  if (tid < NK) pcnt[(size_t)(b * NSL + sl) * NK + tid] = (float)hist[tid];
}

// ---------------------------------------------------------------------------
// Finalize A: grid (NK, NB, NG) = 1344 blocks; each reduces 16 slices.
// psum2[b][g][k][c], pcnt2[b][g][k].
// ---------------------------------------------------------------------------
__global__ __launch_bounds__(256)
void proto_finalA(const float* __restrict__ psum,
                  const float* __restrict__ pcnt,
                  float* __restrict__ psum2,
                  float* __restrict__ pcnt2) {
  const int k = blockIdx.x;   // 0..20
  const int b = blockIdx.y;   // 0..7
  const int g = blockIdx.z;   // 0..7
  const int c = threadIdx.x;  // 0..255
  const int sl0 = g * 16;
  float s = 0.f, cnt = 0.f;
#pragma unroll
  for (int j = 0; j < 16; ++j) {
    s += psum[((size_t)(b * NSL + sl0 + j) * NK + k) * NC + c];  // coalesced
    cnt += pcnt[(size_t)(b * NSL + sl0 + j) * NK + k];           // uniform
  }
  psum2[((size_t)(b * NG + g) * NK + k) * NC + c] = s;
  if (c == 0) pcnt2[(size_t)(b * NG + g) * NK + k] = cnt;
}

// ---------------------------------------------------------------------------
// Finalize B: grid (NK); L2-hot 1.4 MB.
// out[k][c] = (1/8) sum_b [sum_g psum2] / (sum_g pcnt2 + eps)
// ---------------------------------------------------------------------------
__global__ __launch_bounds__(256)
void proto_finalB(const float* __restrict__ psum2,
                  const float* __restrict__ pcnt2,
                  float* __restrict__ out) {
  const int k = blockIdx.x;
  const int c = threadIdx.x;
  float a = 0.f;
#pragma unroll
  for (int b = 0; b < NB; ++b) {
    float s = 0.f, cnt = 0.f;
#pragma unroll
    for (int g = 0; g < NG; ++g) {
      s += psum2[((size_t)(b * NG + g) * NK + k) * NC + c];
      cnt += pcnt2[(size_t)(b * NG + g) * NK + k];
    }
    a += s / (cnt + EPS);
  }
  out[(size_t)k * NC + c] = a * 0.125f;
}

extern "C" void kernel_launch(void* const* d_in, const int* in_sizes, int n_in,
                              void* d_out, int out_size, void* d_ws, size_t ws_size,
                              hipStream_t stream) {
  const float* feats = (const float*)d_in[0];
  const int* masks = (const int*)d_in[1];
  float* out = (float*)d_out;

  // ws: psum [8][128][21][256] (22.0 MB) | pcnt [8][128][21] (86 KB)
  //   | psum2 [8][8][21][256] (1.38 MB)  | pcnt2 [8][8][21] (5.4 KB)
  // All regions fully overwritten before read; no memset needed.
  float* psum = (float*)d_ws;
  float* pcnt = psum + (size_t)NB * NSL * NK * NC;
  float* psum2 = pcnt + (size_t)NB * NSL * NK;
  float* pcnt2 = psum2 + (size_t)NB * NG * NK * NC;

  proto_main<<<dim3(64, NB, 2), 256, 0, stream>>>(feats, masks, psum, pcnt);
  proto_finalA<<<dim3(NK, NB, NG), 256, 0, stream>>>(psum, pcnt, psum2, pcnt2);
  proto_finalB<<<dim3(NK), 256, 0, stream>>>(psum2, pcnt2, out);
}